// Round 1
// baseline (119.046 us; speedup 1.0000x reference)
//
#include <hip/hip_runtime.h>

typedef __attribute__((ext_vector_type(8))) short short8;
typedef __attribute__((ext_vector_type(4))) float floatx4;

#define FDIM 512
#define HDIM 256

__device__ __forceinline__ unsigned short f2bf(float f) {
  unsigned int u = __float_as_uint(f);
  u += 0x7fffu + ((u >> 16) & 1u);   // round-to-nearest-even
  return (unsigned short)(u >> 16);
}

__device__ __forceinline__ short8 pack2(float4 a, float4 b) {
  short8 r;
  r[0] = (short)f2bf(a.x); r[1] = (short)f2bf(a.y);
  r[2] = (short)f2bf(a.z); r[3] = (short)f2bf(a.w);
  r[4] = (short)f2bf(b.x); r[5] = (short)f2bf(b.y);
  r[6] = (short)f2bf(b.z); r[7] = (short)f2bf(b.w);
  return r;
}

__device__ __forceinline__ float fast_tanh(float x) {
  x = fminf(15.0f, fmaxf(-15.0f, x));
  float e = __expf(2.0f * x);
  return (e - 1.0f) / (e + 1.0f);
}

__device__ __forceinline__ void gload_lds16(const void* g, void* l) {
  __builtin_amdgcn_global_load_lds(
      (const __attribute__((address_space(1))) unsigned int*)g,
      (__attribute__((address_space(3))) unsigned int*)l, 16, 0, 0);
}

// K0: pack W1 [512][256] fp32 -> W1B bf16 fragment-major:
// element index = s*8192 + oct*2048 + n*8 + e   (k = s*32 + oct*8 + e)
// Blocks < 128 also zero out (re-poison safety; out accumulated by atomics).
__global__ void __launch_bounds__(256)
k0_pack_w1(const float* __restrict__ W1, unsigned short* __restrict__ W1B,
           float* __restrict__ out) {
  int tid = threadIdx.x;
  int idx = blockIdx.x * 256 + tid;           // 0..131071
  if (blockIdx.x < 128) out[blockIdx.x * 256 + tid] = 0.0f;   // 32768 floats
  int k = idx >> 8;                           // 0..511
  int n = idx & 255;
  int s = k >> 5, r = k & 31, oct = r >> 3, e = r & 7;
  W1B[s * 8192 + oct * 2048 + n * 8 + e] = f2bf(W1[idx]);
}

// K1 fused: scores + exp + UNNORMALIZED per-bag weighted sum of X.
// 128 rows/block, 8 waves (2 row-groups x 4 col-groups), BK=32, 16 steps.
// Full bf16 X tile kept in LDS (As, 128 KB, XOR-swizzled rows) and re-used
// by phase 2 (bag-sum) -> X is read from HBM exactly ONCE.
// LDS: As 131072 + Bs0 16384 + Bs1 16384 = 163840 B (epilogue scratch
// aliases Bs0, which is dead after step 14; last step reads Bs1).
__global__ void __launch_bounds__(512)
k1_fused(const float* __restrict__ X,
         const unsigned short* __restrict__ W1B,
         const float* __restrict__ b1,
         const float* __restrict__ W2,
         const int* __restrict__ bag_sizes,
         int nbags,
         float* __restrict__ out,
         float* __restrict__ partials) {
  __shared__ __align__(16) unsigned char smem[163840];
  unsigned short* As  = (unsigned short*)smem;             // [slot 64][row 128][e 8]
  unsigned short* Bs0 = (unsigned short*)(smem + 131072);  // 16 KB
  unsigned short* Bs1 = (unsigned short*)(smem + 147456);  // 16 KB
  float* scpart = (float*)(smem + 131072);                 // alias Bs0: [4][128]
  float* es_s   = (float*)(smem + 131072 + 2048);          // alias: [128]
  float* wsum_s = (float*)(smem + 131072 + 2560);          // alias: [2]

  const int tid  = threadIdx.x;
  const int wid  = tid >> 6;          // 0..7
  const int lane = tid & 63;
  const int l15  = lane & 15;
  const int l4   = lane >> 4;
  const int wr   = wid >> 2;          // row-group 0/1
  const int wn   = wid & 3;           // col-group 0..3
  const long row0 = (long)blockIdx.x * 128;

  floatx4 acc[4][4];
  #pragma unroll
  for (int m = 0; m < 4; m++)
    #pragma unroll
    for (int n = 0; n < 4; n++)
      acc[m][n] = (floatx4){0.f, 0.f, 0.f, 0.f};

  // A staging map: thread -> (row = tid>>2, octet = tid&3 -> 8 consecutive k)
  const int arow = tid >> 2;                    // 0..127
  const int aoct = tid & 3;                     // octet within 32-k step
  const float* xsrc = X + (row0 + arow) * FDIM + aoct * 8;

  // Prefetch A two steps ahead (two register sets), B one step ahead (dbuf).
  float4 va0, va1, vb0, vb1;
  { const float4* pp = (const float4*)xsrc;        va0 = pp[0]; va1 = pp[1]; }
  { const float4* pp = (const float4*)(xsrc + 32); vb0 = pp[0]; vb1 = pp[1]; }
  #pragma unroll
  for (int i = 0; i < 2; ++i)
    gload_lds16(W1B + (i * 512 + tid) * 8, Bs0 + (i * 512 + wid * 64) * 8);

  for (int t = 0; t < 16; ++t) {
    unsigned short* Bcur = (t & 1) ? Bs1 : Bs0;
    {   // store As(t); compiler inserts the vmcnt wait for the A regs here
      int slot = t * 4 + aoct;
      unsigned short* dst = As + (slot * 128 + (arow ^ (slot & 7))) * 8;
      if ((t & 1) == 0) *(short8*)dst = pack2(va0, va1);
      else              *(short8*)dst = pack2(vb0, vb1);
    }
    __syncthreads();   // As(t) visible; vmcnt(0) drains B(t) gloads into Bcur
    if (t < 14) {      // A(t+2) -> just-freed register set, hidden under 2 steps
      const float4* pp = (const float4*)(xsrc + (t + 2) * 32);
      if ((t & 1) == 0) { va0 = pp[0]; va1 = pp[1]; }
      else              { vb0 = pp[0]; vb1 = pp[1]; }
    }
    if (t < 15) {      // B(t+1) -> other buffer, hidden under compute(t)
      unsigned short* Bn = (t & 1) ? Bs0 : Bs1;
      #pragma unroll
      for (int i = 0; i < 2; ++i)
        gload_lds16(W1B + (t + 1) * 8192 + (i * 512 + tid) * 8,
                    Bn + (i * 512 + wid * 64) * 8);
    }
    // compute(t): 4 A-frags, 4 B-frags, 16 MFMA per wave
    const int slotc = t * 4 + l4;
    const int gg = slotc & 7;
    short8 af[4];
    #pragma unroll
    for (int m = 0; m < 4; ++m)
      af[m] = *(const short8*)(As + (slotc * 128 + ((wr * 64 + m * 16 + l15) ^ gg)) * 8);
    #pragma unroll
    for (int n = 0; n < 4; ++n) {
      short8 bfr = *(const short8*)(Bcur + (l4 * 256 + wn * 64 + n * 16 + l15) * 8);
      #pragma unroll
      for (int m = 0; m < 4; ++m)
        acc[m][n] = __builtin_amdgcn_mfma_f32_16x16x32_bf16(af[m], bfr, acc[m][n], 0, 0, 0);
    }
  }

  // epilogue: score = sum_c tanh(H + b1[c]) * W2[c]  over this wave's 64 cols
  // (scpart aliases Bs0: dead, last read at step 14, all waves past barrier 15)
  float rowacc[16];
  #pragma unroll
  for (int i = 0; i < 16; i++) rowacc[i] = 0.f;
  #pragma unroll
  for (int n = 0; n < 4; n++) {
    int c = wn * 64 + n * 16 + l15;
    float b1c = b1[c];
    float w2c = W2[c];
    #pragma unroll
    for (int m = 0; m < 4; m++)
      #pragma unroll
      for (int j = 0; j < 4; j++) {
        float h = fast_tanh(acc[m][n][j] + b1c);
        rowacc[m * 4 + j] = fmaf(h, w2c, rowacc[m * 4 + j]);
      }
  }
  #pragma unroll
  for (int i = 0; i < 16; i++) {
    float v = rowacc[i];
    v += __shfl_xor(v, 1, 64);
    v += __shfl_xor(v, 2, 64);
    v += __shfl_xor(v, 4, 64);
    v += __shfl_xor(v, 8, 64);
    rowacc[i] = v;
  }
  if (l15 == 0) {
    #pragma unroll
    for (int m = 0; m < 4; m++)
      #pragma unroll
      for (int j = 0; j < 4; j++)
        scpart[wn * 128 + wr * 64 + m * 16 + l4 * 4 + j] = rowacc[m * 4 + j];
  }
  __syncthreads();

  // es (LDS only) + block partial Z
  if (tid < 128) {
    float sv = scpart[0 * 128 + tid] + scpart[1 * 128 + tid] +
               scpart[2 * 128 + tid] + scpart[3 * 128 + tid];
    float ev = __expf(sv);
    es_s[tid] = ev;
    float v = ev;
    v += __shfl_xor(v, 1, 64);
    v += __shfl_xor(v, 2, 64);
    v += __shfl_xor(v, 4, 64);
    v += __shfl_xor(v, 8, 64);
    v += __shfl_xor(v, 16, 64);
    v += __shfl_xor(v, 32, 64);
    if (lane == 0) wsum_s[wid] = v;
  }
  __syncthreads();
  if (tid == 0) partials[blockIdx.x] = wsum_s[0] + wsum_s[1];

  // ---- phase 2: out[bag] += sum_r es[r] * X_bf16[r]  (unnormalized) ----
  // thread = (chunk s 0..63 = 8 features, parity p 0..7 over rows)
  const int s  = tid >> 3;
  const int p  = tid & 7;
  const int gp = s & 7;                          // As row-swizzle for this slot
  const int fbase = (s >> 2) * 32 + (s & 3) * 8; // k = (s>>2)*32 + (s&3)*8 + e
  const unsigned short* abase = As + s * 1024;

  // bag of first row (uniform across block)
  int bag = 0; long cum = 0;
  while (bag + 1 < nbags && cum + (long)bag_sizes[bag] <= row0) {
    cum += bag_sizes[bag]; ++bag;
  }
  long bagEnd = cum + (long)bag_sizes[bag];

  int rs = 0;
  while (rs < 128) {
    int se = (int)(bagEnd - row0 < 128 ? bagEnd - row0 : 128);
    float pa[8];
    #pragma unroll
    for (int e = 0; e < 8; ++e) pa[e] = 0.f;
    #pragma unroll
    for (int j = 0; j < 16; ++j) {
      int r = p + 8 * j;
      if (r >= rs && r < se) {
        float w = es_s[r];
        short8 xv = *(const short8*)(abase + ((r ^ gp) * 8));
        const unsigned int* ui = (const unsigned int*)&xv;
        #pragma unroll
        for (int d = 0; d < 4; ++d) {
          float xlo = __uint_as_float(ui[d] << 16);
          float xhi = __uint_as_float(ui[d] & 0xffff0000u);
          pa[2 * d]     = fmaf(xlo, w, pa[2 * d]);
          pa[2 * d + 1] = fmaf(xhi, w, pa[2 * d + 1]);
        }
      }
    }
    // reduce over parity p (lane bits 0..2; same s)
    #pragma unroll
    for (int e = 0; e < 8; ++e) {
      pa[e] += __shfl_xor(pa[e], 1, 64);
      pa[e] += __shfl_xor(pa[e], 2, 64);
      pa[e] += __shfl_xor(pa[e], 4, 64);
    }
    if (p == 0 && se > rs) {
      float* op = out + (long)bag * FDIM + fbase;
      #pragma unroll
      for (int e = 0; e < 8; ++e) atomicAdd(op + e, pa[e]);
    }
    rs = se;
    if (rs < 128) {
      ++bag;
      if (bag >= nbags) { bagEnd = row0 + 128; bag = nbags - 1; }
      else bagEnd += (long)bag_sizes[bag];
    }
  }
}

// K2: Z = sum(partials) (redundant per block); out *= 1/Z
__global__ void __launch_bounds__(256)
k2_scale(const float* __restrict__ partials, int nparts, float* __restrict__ out) {
  __shared__ float wred[4];
  int tid = threadIdx.x;
  float sL = 0.f;
  for (int j = tid; j < nparts; j += 256) sL += partials[j];
  #pragma unroll
  for (int m = 1; m < 64; m <<= 1) sL += __shfl_xor(sL, m, 64);
  if ((tid & 63) == 0) wred[tid >> 6] = sL;
  __syncthreads();
  float invZ = 1.0f / (wred[0] + wred[1] + wred[2] + wred[3]);
  int i = blockIdx.x * 256 + tid;
  out[i] = out[i] * invZ;
}

extern "C" void kernel_launch(void* const* d_in, const int* in_sizes, int n_in,
                              void* d_out, int out_size, void* d_ws, size_t ws_size,
                              hipStream_t stream) {
  const float* X         = (const float*)d_in[0];
  const int*   bag_sizes = (const int*)d_in[1];
  const float* W1        = (const float*)d_in[2];
  const float* b1        = (const float*)d_in[3];
  const float* W2        = (const float*)d_in[4];
  // b2 (d_in[5]) cancels in the global softmax — unused.
  float* out = (float*)d_out;

  const int T     = in_sizes[0] / FDIM;   // 131072
  const int nbags = in_sizes[1];          // 64
  const int nblk  = T / 128;              // 1024

  char* ws = (char*)d_ws;
  unsigned short* W1B = (unsigned short*)ws;                     // 262144 B
  float* partials = (float*)(ws + 262144);                       // 4096 B

  hipLaunchKernelGGL(k0_pack_w1, dim3(512), dim3(256), 0, stream, W1, W1B, out);
  hipLaunchKernelGGL(k1_fused, dim3(nblk), dim3(512), 0, stream,
                     X, W1B, b1, W2, bag_sizes, nbags, out, partials);
  hipLaunchKernelGGL(k2_scale, dim3((nbags * FDIM) / 256), dim3(256), 0, stream,
                     partials, nblk, out);
}

// Round 2
// 109.430 us; speedup vs baseline: 1.0879x; 1.0879x over previous
//
#include <hip/hip_runtime.h>

typedef __attribute__((ext_vector_type(8))) short short8;
typedef __attribute__((ext_vector_type(4))) float floatx4;

#define FDIM 512
#define HDIM 256

__device__ __forceinline__ unsigned short f2bf(float f) {
  unsigned int u = __float_as_uint(f);
  u += 0x7fffu + ((u >> 16) & 1u);   // round-to-nearest-even
  return (unsigned short)(u >> 16);
}

__device__ __forceinline__ short8 pack2(floatx4 a, floatx4 b) {
  short8 r;
  r[0] = (short)f2bf(a[0]); r[1] = (short)f2bf(a[1]);
  r[2] = (short)f2bf(a[2]); r[3] = (short)f2bf(a[3]);
  r[4] = (short)f2bf(b[0]); r[5] = (short)f2bf(b[1]);
  r[6] = (short)f2bf(b[2]); r[7] = (short)f2bf(b[3]);
  return r;
}

__device__ __forceinline__ float fast_tanh(float x) {
  x = fminf(15.0f, fmaxf(-15.0f, x));
  float e = __expf(2.0f * x);
  return (e - 1.0f) / (e + 1.0f);
}

__device__ __forceinline__ void gload_lds16(const void* g, void* l) {
  __builtin_amdgcn_global_load_lds(
      (const __attribute__((address_space(1))) unsigned int*)g,
      (__attribute__((address_space(3))) unsigned int*)l, 16, 0, 0);
}

// Issue 2 global_load_dwordx4 (8 floats) via asm; results NOT ready until the
// counted s_waitcnt vmcnt(N) fires (manual ledger in k1's main loop).
#define GLOAD_SET(r0, r1, p)                                                   \
  do {                                                                         \
    asm volatile("global_load_dwordx4 %0, %1, off"                             \
                 : "=v"(r0) : "v"(p) : "memory");                              \
    asm volatile("global_load_dwordx4 %0, %1, off offset:16"                   \
                 : "=v"(r1) : "v"(p) : "memory");                              \
  } while (0)

// K0: pack W1 [512][256] fp32 -> W1B bf16 fragment-major:
// element index = s*8192 + oct*2048 + n*8 + e   (k = s*32 + oct*8 + e)
// Blocks < 128 also zero out (re-poison safety; out accumulated by atomics).
__global__ void __launch_bounds__(256)
k0_pack_w1(const float* __restrict__ W1, unsigned short* __restrict__ W1B,
           float* __restrict__ out) {
  int tid = threadIdx.x;
  int idx = blockIdx.x * 256 + tid;           // 0..131071
  if (blockIdx.x < 128) out[blockIdx.x * 256 + tid] = 0.0f;   // 32768 floats
  int k = idx >> 8;                           // 0..511
  int n = idx & 255;
  int s = k >> 5, r = k & 31, oct = r >> 3, e = r & 7;
  W1B[s * 8192 + oct * 2048 + n * 8 + e] = f2bf(W1[idx]);
}

// K1 fused: scores + exp + UNNORMALIZED per-bag weighted sum of X.
// 128 rows/block, 8 waves, BK=32, 16 steps, full bf16 X tile in LDS (As).
// Pipeline: raw s_barrier + counted vmcnt (NO __syncthreads drain in loop).
// Per-thread vmem issue order (2 loads each): ... A(t) | B(t) A(t+1) | ...
//   at step t head: outstanding = [A(t)2, B(t)2, A(t+1)2]
//   wait vmcnt(4) -> A(t) regs ready (pack+ds_write)
//   wait vmcnt(2) -> B(t) gloads landed (everyone waits own, then barrier)
//   t=15 tail (no A(16)): [A(15)2, B(15)2] -> vmcnt(2) / vmcnt(0)
// Hazard ledger:
//   As: write-once per slot, no WAR; visibility via lgkmcnt(0)+barrier.
//   Bs[(t+1)&1] gload issued after barrier(t) => all waves past compute(t-1)
//     which read that buffer. Double-buffered, so compute(t) reads the other.
//   scpart/es_s alias Bs0: last Bs0 read is compute(14); all waves are past
//     barrier(15) before any wave writes scpart.
__global__ void __launch_bounds__(512)
k1_fused(const float* __restrict__ X,
         const unsigned short* __restrict__ W1B,
         const float* __restrict__ b1,
         const float* __restrict__ W2,
         const int* __restrict__ bag_sizes,
         int nbags,
         float* __restrict__ out,
         float* __restrict__ partials) {
  __shared__ __align__(16) unsigned char smem[163840];
  unsigned short* As  = (unsigned short*)smem;             // [slot 64][row 128][e 8]
  unsigned short* Bs0 = (unsigned short*)(smem + 131072);  // 16 KB
  unsigned short* Bs1 = (unsigned short*)(smem + 147456);  // 16 KB
  float* scpart = (float*)(smem + 131072);                 // alias Bs0: [4][128]
  float* es_s   = (float*)(smem + 131072 + 2048);          // alias: [128]
  float* wsum_s = (float*)(smem + 131072 + 2560);          // alias: [2]

  const int tid  = threadIdx.x;
  const int wid  = tid >> 6;          // 0..7
  const int lane = tid & 63;
  const int l15  = lane & 15;
  const int l4   = lane >> 4;
  const int wr   = wid >> 2;          // row-group 0/1
  const int wn   = wid & 3;           // col-group 0..3
  const long row0 = (long)blockIdx.x * 128;

  floatx4 acc[4][4];
  #pragma unroll
  for (int m = 0; m < 4; m++)
    #pragma unroll
    for (int n = 0; n < 4; n++)
      acc[m][n] = (floatx4){0.f, 0.f, 0.f, 0.f};

  // A staging map: thread -> (row = tid>>2, octet = tid&3 -> 8 consecutive k)
  const int arow = tid >> 2;                    // 0..127
  const int aoct = tid & 3;                     // octet within 32-k step
  const float* xsrc = X + (row0 + arow) * FDIM + aoct * 8;

  floatx4 va0, va1, vb0, vb1;       // two A register sets (depth-2 prefetch)

  // Prologue issue order: A(0), B(0), A(1)  => steady-state ledger from t=0.
  GLOAD_SET(va0, va1, xsrc);
  #pragma unroll
  for (int i = 0; i < 2; ++i)
    gload_lds16(W1B + (i * 512 + tid) * 8, Bs0 + (i * 512 + wid * 64) * 8);
  GLOAD_SET(vb0, vb1, xsrc + 32);

  #pragma unroll
  for (int t = 0; t < 16; ++t) {
    unsigned short* Bcur = (t & 1) ? Bs1 : Bs0;
    // ---- retire A(t) regs ----
    if (t < 15) asm volatile("s_waitcnt vmcnt(4)" ::: "memory");
    else        asm volatile("s_waitcnt vmcnt(2)" ::: "memory");
    __builtin_amdgcn_sched_barrier(0);
    {
      short8 a = ((t & 1) == 0) ? pack2(va0, va1) : pack2(vb0, vb1);
      int slot = t * 4 + aoct;
      *(short8*)(As + (slot * 128 + (arow ^ (slot & 7))) * 8) = a;
    }
    // ---- own ds_write committed; own B(t) gloads landed; then barrier ----
    asm volatile("s_waitcnt lgkmcnt(0)" ::: "memory");
    if (t < 15) asm volatile("s_waitcnt vmcnt(2)" ::: "memory");
    else        asm volatile("s_waitcnt vmcnt(0)" ::: "memory");
    __builtin_amdgcn_sched_barrier(0);
    __builtin_amdgcn_s_barrier();
    // ---- issue next-tile loads (stay in flight across future barriers) ----
    if (t < 15) {      // B(t+1) -> other buffer (readers of it are done)
      unsigned short* Bn = (t & 1) ? Bs0 : Bs1;
      #pragma unroll
      for (int i = 0; i < 2; ++i)
        gload_lds16(W1B + (t + 1) * 8192 + (i * 512 + tid) * 8,
                    Bn + (i * 512 + wid * 64) * 8);
    }
    if (t < 14) {      // A(t+2) -> just-consumed register set
      const float* pp = xsrc + (t + 2) * 32;
      if ((t & 1) == 0) GLOAD_SET(va0, va1, pp);
      else              GLOAD_SET(vb0, vb1, pp);
    }
    // ---- compute(t): 4 A-frags x 4 B-frags, 16 MFMA per wave ----
    const int slotc = t * 4 + l4;
    const int gg = slotc & 7;
    short8 af[4];
    #pragma unroll
    for (int m = 0; m < 4; ++m)
      af[m] = *(const short8*)(As + (slotc * 128 + ((wr * 64 + m * 16 + l15) ^ gg)) * 8);
    #pragma unroll
    for (int n = 0; n < 4; ++n) {
      short8 bfr = *(const short8*)(Bcur + (l4 * 256 + wn * 64 + n * 16 + l15) * 8);
      #pragma unroll
      for (int m = 0; m < 4; ++m)
        acc[m][n] = __builtin_amdgcn_mfma_f32_16x16x32_bf16(af[m], bfr, acc[m][n], 0, 0, 0);
    }
  }

  // epilogue: score = sum_c tanh(H + b1[c]) * W2[c]  over this wave's 64 cols
  float rowacc[16];
  #pragma unroll
  for (int i = 0; i < 16; i++) rowacc[i] = 0.f;
  #pragma unroll
  for (int n = 0; n < 4; n++) {
    int c = wn * 64 + n * 16 + l15;
    float b1c = b1[c];
    float w2c = W2[c];
    #pragma unroll
    for (int m = 0; m < 4; m++)
      #pragma unroll
      for (int j = 0; j < 4; j++) {
        float h = fast_tanh(acc[m][n][j] + b1c);
        rowacc[m * 4 + j] = fmaf(h, w2c, rowacc[m * 4 + j]);
      }
  }
  #pragma unroll
  for (int i = 0; i < 16; i++) {
    float v = rowacc[i];
    v += __shfl_xor(v, 1, 64);
    v += __shfl_xor(v, 2, 64);
    v += __shfl_xor(v, 4, 64);
    v += __shfl_xor(v, 8, 64);
    rowacc[i] = v;
  }
  if (l15 == 0) {
    #pragma unroll
    for (int m = 0; m < 4; m++)
      #pragma unroll
      for (int j = 0; j < 4; j++)
        scpart[wn * 128 + wr * 64 + m * 16 + l4 * 4 + j] = rowacc[m * 4 + j];
  }
  __syncthreads();

  // es (LDS only) + block partial Z
  if (tid < 128) {
    float sv = scpart[0 * 128 + tid] + scpart[1 * 128 + tid] +
               scpart[2 * 128 + tid] + scpart[3 * 128 + tid];
    float ev = __expf(sv);
    es_s[tid] = ev;
    float v = ev;
    v += __shfl_xor(v, 1, 64);
    v += __shfl_xor(v, 2, 64);
    v += __shfl_xor(v, 4, 64);
    v += __shfl_xor(v, 8, 64);
    v += __shfl_xor(v, 16, 64);
    v += __shfl_xor(v, 32, 64);
    if (lane == 0) wsum_s[wid] = v;
  }
  __syncthreads();
  if (tid == 0) partials[blockIdx.x] = wsum_s[0] + wsum_s[1];

  // ---- phase 2: out[bag] += sum_r es[r] * X_bf16[r]  (unnormalized) ----
  // thread = (chunk s 0..63 = 8 features, parity p 0..7 over rows)
  const int s  = tid >> 3;
  const int p  = tid & 7;
  const int gp = s & 7;                          // As row-swizzle for this slot
  const int fbase = (s >> 2) * 32 + (s & 3) * 8; // k = (s>>2)*32 + (s&3)*8 + e
  const unsigned short* abase = As + s * 1024;

  // bag of first row (uniform across block)
  int bag = 0; long cum = 0;
  while (bag + 1 < nbags && cum + (long)bag_sizes[bag] <= row0) {
    cum += bag_sizes[bag]; ++bag;
  }
  long bagEnd = cum + (long)bag_sizes[bag];

  int rs = 0;
  while (rs < 128) {
    int se = (int)(bagEnd - row0 < 128 ? bagEnd - row0 : 128);
    float pa[8];
    #pragma unroll
    for (int e = 0; e < 8; ++e) pa[e] = 0.f;
    #pragma unroll
    for (int j = 0; j < 16; ++j) {
      int r = p + 8 * j;
      if (r >= rs && r < se) {
        float w = es_s[r];
        short8 xv = *(const short8*)(abase + ((r ^ gp) * 8));
        const unsigned int* ui = (const unsigned int*)&xv;
        #pragma unroll
        for (int d = 0; d < 4; ++d) {
          float xlo = __uint_as_float(ui[d] << 16);
          float xhi = __uint_as_float(ui[d] & 0xffff0000u);
          pa[2 * d]     = fmaf(xlo, w, pa[2 * d]);
          pa[2 * d + 1] = fmaf(xhi, w, pa[2 * d + 1]);
        }
      }
    }
    // reduce over parity p (lane bits 0..2; same s)
    #pragma unroll
    for (int e = 0; e < 8; ++e) {
      pa[e] += __shfl_xor(pa[e], 1, 64);
      pa[e] += __shfl_xor(pa[e], 2, 64);
      pa[e] += __shfl_xor(pa[e], 4, 64);
    }
    if (p == 0 && se > rs) {
      float* op = out + (long)bag * FDIM + fbase;
      #pragma unroll
      for (int e = 0; e < 8; ++e) atomicAdd(op + e, pa[e]);
    }
    rs = se;
    if (rs < 128) {
      ++bag;
      if (bag >= nbags) { bagEnd = row0 + 128; bag = nbags - 1; }
      else bagEnd += (long)bag_sizes[bag];
    }
  }
}

// K2: Z = sum(partials) (redundant per block); out *= 1/Z
__global__ void __launch_bounds__(256)
k2_scale(const float* __restrict__ partials, int nparts, float* __restrict__ out) {
  __shared__ float wred[4];
  int tid = threadIdx.x;
  float sL = 0.f;
  for (int j = tid; j < nparts; j += 256) sL += partials[j];
  #pragma unroll
  for (int m = 1; m < 64; m <<= 1) sL += __shfl_xor(sL, m, 64);
  if ((tid & 63) == 0) wred[tid >> 6] = sL;
  __syncthreads();
  float invZ = 1.0f / (wred[0] + wred[1] + wred[2] + wred[3]);
  int i = blockIdx.x * 256 + tid;
  out[i] = out[i] * invZ;
}

extern "C" void kernel_launch(void* const* d_in, const int* in_sizes, int n_in,
                              void* d_out, int out_size, void* d_ws, size_t ws_size,
                              hipStream_t stream) {
  const float* X         = (const float*)d_in[0];
  const int*   bag_sizes = (const int*)d_in[1];
  const float* W1        = (const float*)d_in[2];
  const float* b1        = (const float*)d_in[3];
  const float* W2        = (const float*)d_in[4];
  // b2 (d_in[5]) cancels in the global softmax — unused.
  float* out = (float*)d_out;

  const int T     = in_sizes[0] / FDIM;   // 131072
  const int nbags = in_sizes[1];          // 64
  const int nblk  = T / 128;              // 1024

  char* ws = (char*)d_ws;
  unsigned short* W1B = (unsigned short*)ws;                     // 262144 B
  float* partials = (float*)(ws + 262144);                       // 4096 B

  hipLaunchKernelGGL(k0_pack_w1, dim3(512), dim3(256), 0, stream, W1, W1B, out);
  hipLaunchKernelGGL(k1_fused, dim3(nblk), dim3(512), 0, stream,
                     X, W1B, b1, W2, bag_sizes, nbags, out, partials);
  hipLaunchKernelGGL(k2_scale, dim3((nbags * FDIM) / 256), dim3(256), 0, stream,
                     partials, nblk, out);
}